// Round 6
// baseline (253.164 us; speedup 1.0000x reference)
//
#include <hip/hip_runtime.h>
#include <math.h>

#define DIM 1024
#define NEXP 64
#define TOPK 8
#define BM 128              // tokens per gemm block
#define BK 16               // k-chunk (4 x 16B chunks per row)
#define THREADS_G 128       // 2 waves
#define THREADS_F 256
#define SPAD 68             // epilogue stage row stride (16B aligned, 2-way banks)
#define LPAD 65             // finalize logits row stride (scalar access, 2-way)

// global -> LDS direct DMA, 16B per lane (dest must be uniform base + lane*16)
__device__ __forceinline__ void gload16(const float* g, float* l) {
    __builtin_amdgcn_global_load_lds(
        (const __attribute__((address_space(1))) void*)g,
        (__attribute__((address_space(3))) void*)l, 16, 0, 0);
}

// ---------------- kernel 1: partial GEMM (one K-slice per block) ----------------
// grid (ntok/BM, ksplit); 128 threads; 8x8 register tile.
// Thread map: trow = tid>>3 (0..15), tcol = tid&7 (0..7)
//   tokens  trow + 16*i (i<8), experts tcol + 8*j (j<8)
__global__ __launch_bounds__(THREADS_G, 2)
void router_gemm_partial(const float* __restrict__ x,
                         const float* __restrict__ W,
                         float* __restrict__ part,   // [ksplit][ntok][64]
                         int ntok, int kq)
{
    // 34.8 KB shared arena: gemm tiles (24 KB) overlaid by epilogue stage (34 KB)
    __shared__ float smem[BM * SPAD];
    float (*x_s)[BM][BK]   = (float (*)[BM][BK])smem;            // [2][128][16]
    float (*w_s)[NEXP][BK] = (float (*)[NEXP][BK])(smem + 4096); // [2][64][16]

    const int tid  = threadIdx.x;
    const int trow = tid >> 3;                 // 0..15
    const int tcol = tid & 7;                  // 0..7
    const int lane = tid & 63;
    const int wv   = tid >> 6;                 // wave 0..1
    const int tok0 = blockIdx.x * BM;
    const int half = blockIdx.y;
    const int k0   = half * kq;
    const int nchunk = kq >> 4;                // kq/BK

    float acc[8][8];
#pragma unroll
    for (int i = 0; i < 8; ++i)
#pragma unroll
        for (int j = 0; j < 8; ++j) acc[i][j] = 0.f;

    // staging: each wave-issue covers 16 rows x 4 chunks (64 lanes x 16B).
    // LDS[r][c] holds logical chunk c^(r&3): linear dest, swizzled source.
    const int rl = lane >> 2;                  // 0..15 row within issue
    const int c  = lane & 3;                   // phys 16B chunk
    auto stage = [&](int buf, int kc) {
        const int kbase = k0 + kc * BK;
#pragma unroll
        for (int m = 0; m < 4; ++m) {          // x: 4 issues x 16 rows per wave
            int r  = wv * 64 + m * 16 + rl;
            int cs = c ^ (r & 3);
            gload16(x + (size_t)(tok0 + r) * DIM + kbase + cs * 4,
                    &x_s[buf][r][c * 4]);
        }
#pragma unroll
        for (int m = 0; m < 2; ++m) {          // W: 2 issues x 16 rows per wave
            int r  = wv * 32 + m * 16 + rl;
            int cs = c ^ (r & 3);
            gload16(W + (size_t)r * DIM + kbase + cs * 4,
                    &w_s[buf][r][c * 4]);
        }
    };

    auto compute = [&](int buf) {
#pragma unroll
        for (int k4 = 0; k4 < 4; ++k4) {
            const int cx = (k4 ^ (trow & 3)) * 4;   // phys chunk -> logical k4
            const int cw = (k4 ^ (tcol & 3)) * 4;
            float4 xa[8];
#pragma unroll
            for (int i = 0; i < 8; ++i)
                xa[i] = *(const float4*)&x_s[buf][trow + 16 * i][cx];
            // two wa half-groups to cap live registers (acc64+xa32+wa16)
#pragma unroll
            for (int jh = 0; jh < 2; ++jh) {
                float4 wa[4];
#pragma unroll
                for (int j = 0; j < 4; ++j)
                    wa[j] = *(const float4*)&w_s[buf][tcol + 8 * (jh * 4 + j)][cw];
#pragma unroll
                for (int i = 0; i < 8; ++i)
#pragma unroll
                    for (int j = 0; j < 4; ++j) {
                        float* a = &acc[i][jh * 4 + j];
                        *a = fmaf(xa[i].x, wa[j].x, *a);
                        *a = fmaf(xa[i].y, wa[j].y, *a);
                        *a = fmaf(xa[i].z, wa[j].z, *a);
                        *a = fmaf(xa[i].w, wa[j].w, *a);
                    }
            }
        }
    };

    stage(0, 0);
    __syncthreads();
    for (int kc = 0; kc < nchunk; ++kc) {
        const int cur = kc & 1;
        if (kc + 1 < nchunk) stage(cur ^ 1, kc + 1);   // issue-early DMA
        compute(cur);                                   // hides HBM latency
        __syncthreads();                                // next buf resident
    }

    // ---- epilogue: stage partial tile in LDS (overlay), then coalesced f4 out
#pragma unroll
    for (int i = 0; i < 8; ++i)
#pragma unroll
        for (int j = 0; j < 8; ++j)
            smem[(trow + 16 * i) * SPAD + tcol + 8 * j] = acc[i][j];
    __syncthreads();

    float* dst = part + ((size_t)half * ntok + tok0) * NEXP;
#pragma unroll
    for (int it = 0; it < 16; ++it) {
        int v = tid + it * THREADS_G;          // 2048 f4
        int r = v >> 4, c4 = (v & 15) * 4;
        *(float4*)(dst + (size_t)r * NEXP + c4) = *(const float4*)&smem[r * SPAD + c4];
    }
}

// ---------------- kernel 2: reduce slices + bias + top-8 + softmax ----------------
// grid ntok/64; 256 threads; 64 tokens per block.
__global__ __launch_bounds__(THREADS_F, 2)
void router_topk_finalize(const float* __restrict__ part,
                          const float* __restrict__ b,
                          float* __restrict__ out_probs,
                          float* __restrict__ out_idx,
                          int ntok, int ksplit)
{
    __shared__ float logits_s[64][LPAD];
    __shared__ float topk_s[64][TOPK];

    const int tid  = threadIdx.x;
    const int tok0 = blockIdx.x * 64;

    // load + reduce slices (ascending h) + bias
#pragma unroll
    for (int it = 0; it < 4; ++it) {
        int v = tid + it * THREADS_F;          // 1024 f4 = 64x64 floats
        int r = v >> 4, c4 = (v & 15) * 4;
        float4 s = make_float4(0.f, 0.f, 0.f, 0.f);
        for (int h = 0; h < ksplit; ++h) {
            float4 a = *(const float4*)(part + ((size_t)h * ntok + tok0 + r) * NEXP + c4);
            s.x += a.x; s.y += a.y; s.z += a.z; s.w += a.w;
        }
        float4 bv = *(const float4*)(b + c4);
        logits_s[r][c4 + 0] = s.x + bv.x;
        logits_s[r][c4 + 1] = s.y + bv.y;
        logits_s[r][c4 + 2] = s.z + bv.z;
        logits_s[r][c4 + 3] = s.w + bv.w;
    }
    __syncthreads();

    if (tid < 64) {
        const int t = tid;
        float pv[TOPK]; int pi[TOPK];
#pragma unroll
        for (int k = 0; k < TOPK; ++k) {
            float vmax = -INFINITY; int imax = 0;
#pragma unroll
            for (int e = 0; e < NEXP; ++e) {
                float v = logits_s[t][e];
                if (v > vmax) { vmax = v; imax = e; }   // strict > == lowest-index tie-break
            }
            pv[k] = vmax; pi[k] = imax;
            logits_s[t][imax] = -INFINITY;
        }
        float p[TOPK]; float s = 0.f;
#pragma unroll
        for (int k = 0; k < TOPK; ++k) { p[k] = __expf(pv[k] - pv[0]); s += p[k]; }
        float inv = 1.f / s;

#pragma unroll
        for (int e = 0; e < NEXP; ++e) logits_s[t][e] = 0.f;
#pragma unroll
        for (int k = 0; k < TOPK; ++k) {
            logits_s[t][pi[k]] = p[k] * inv;
            topk_s[t][k] = (float)pi[k];
        }
    }
    __syncthreads();

#pragma unroll
    for (int it = 0; it < 4; ++it) {
        int v = tid + it * THREADS_F;
        int r = v >> 4, c4 = (v & 15) * 4;
        float4 z = make_float4(logits_s[r][c4], logits_s[r][c4 + 1],
                               logits_s[r][c4 + 2], logits_s[r][c4 + 3]);
        *(float4*)(out_probs + (size_t)(tok0 + r) * NEXP + c4) = z;
    }
    if (tid < 128) {
        int r = tid >> 1, c4 = tid & 1;
        float4 z = *(const float4*)&topk_s[r][c4 * 4];
        *(float4*)(out_idx + (size_t)(tok0 + r) * TOPK + c4 * 4) = z;
    }
}

extern "C" void kernel_launch(void* const* d_in, const int* in_sizes, int n_in,
                              void* d_out, int out_size, void* d_ws, size_t ws_size,
                              hipStream_t stream) {
    const float* x = (const float*)d_in[0];
    const float* W = (const float*)d_in[1];
    const float* b = (const float*)d_in[2];
    float* out = (float*)d_out;

    const int ntok = in_sizes[0] / DIM;            // 32768
    float* out_probs = out;                         // [ntok, 64]
    float* out_idx   = out + (size_t)ntok * NEXP;   // [ntok, 8] as float values
    float* part      = (float*)d_ws;                // [ksplit][ntok][64]

    // KSPLIT=4 needs 33.6 MB scratch; fall back to 2 (16.8 MB, round-5 proven) if short
    const size_t need4 = (size_t)4 * ntok * NEXP * sizeof(float);
    const int ksplit = (ws_size >= need4) ? 4 : 2;
    const int kq = DIM / ksplit;

    router_gemm_partial<<<dim3(ntok / BM, ksplit), THREADS_G, 0, stream>>>(x, W, part, ntok, kq);
    router_topk_finalize<<<ntok / 64, THREADS_F, 0, stream>>>(part, b, out_probs, out_idx, ntok, ksplit);
}

// Round 7
// 229.310 us; speedup vs baseline: 1.1040x; 1.1040x over previous
//
#include <hip/hip_runtime.h>
#include <math.h>

#define DIM 1024
#define NEXP 64
#define TOPK 8
#define BM 32                  // tokens per block
#define NCH 32                 // K chunks of 32
#define THREADS 128            // 2 waves
#define LPAD 65
#define WARR 131072            // bytes per W split array: 32 kc * 4096

typedef __attribute__((ext_vector_type(8))) short short8v;
typedef __attribute__((ext_vector_type(4))) float f32x4;
typedef __attribute__((ext_vector_type(4))) unsigned short ushort4v;

// RNE fp32 -> bf16 bits; 'back' = bf16 value as fp32
__device__ __forceinline__ unsigned short rne_bf16(float f, float& back) {
    unsigned u = __builtin_bit_cast(unsigned, f);
    unsigned r = (u + 0x7FFFu + ((u >> 16) & 1u)) >> 16;
    back = __builtin_bit_cast(float, r << 16);
    return (unsigned short)r;
}

__device__ __forceinline__ void gload16(const void* g, void* l) {
    __builtin_amdgcn_global_load_lds(
        (const __attribute__((address_space(1))) void*)g,
        (__attribute__((address_space(3))) void*)l, 16, 0, 0);
}

// ---- pre-kernel: W[64][1024] fp32 -> 3 bf16 split arrays, pre-swizzled ----
// ws layout: array a in [0,3): [kc][e][c] 16B chunks; chunk c holds logical
// k-octet g = c ^ (e&3)  (so linear DMA + swizzled read reconstructs).
__global__ __launch_bounds__(256)
void wconv_kernel(const float* __restrict__ W, char* __restrict__ ws) {
    int id = blockIdx.x * 256 + threadIdx.x;     // 8192 = 32kc * 64e * 4g
    int kc = id >> 8, rem = id & 255, e = rem >> 2, g = rem & 3;
    const float* src = W + (size_t)e * DIM + kc * 32 + g * 8;
    f32x4 v0 = *(const f32x4*)src;
    f32x4 v1 = *(const f32x4*)(src + 4);
    float xs[8] = {v0.x, v0.y, v0.z, v0.w, v1.x, v1.y, v1.z, v1.w};
    ushort4v h[2], l[2], m[2];
#pragma unroll
    for (int i = 0; i < 8; ++i) {
        float bh, bl, bm;
        unsigned short hh = rne_bf16(xs[i], bh);
        float r1 = xs[i] - bh;
        unsigned short ll = rne_bf16(r1, bl);
        float r2 = r1 - bl;
        unsigned short mm = rne_bf16(r2, bm);
        h[i >> 2][i & 3] = hh; l[i >> 2][i & 3] = ll; m[i >> 2][i & 3] = mm;
    }
    size_t dst = (size_t)kc * 4096 + e * 64 + (size_t)(g ^ (e & 3)) * 16;
    *(ushort4v*)(ws + 0 * WARR + dst)     = h[0];
    *(ushort4v*)(ws + 0 * WARR + dst + 8) = h[1];
    *(ushort4v*)(ws + 1 * WARR + dst)     = l[0];
    *(ushort4v*)(ws + 1 * WARR + dst + 8) = l[1];
    *(ushort4v*)(ws + 2 * WARR + dst)     = m[0];
    *(ushort4v*)(ws + 2 * WARR + dst + 8) = m[1];
}

// ---- fused: MFMA logits + bias + top-8 + softmax + outputs ----
__global__ __launch_bounds__(THREADS, 2)
void router_fused_kernel(const float* __restrict__ x,
                         const char* __restrict__ ws,   // Wh/Wl/Wm split arrays
                         const float* __restrict__ b,
                         float* __restrict__ out_probs,
                         float* __restrict__ out_idx)
{
    __shared__ __align__(16) char warena[2][3][4096];   // 24 KB dbuf W chunk
    __shared__ float logits_s[BM][LPAD];                // 8.3 KB
    __shared__ float topk_s[BM][TOPK];                  // 1 KB

    const int tid   = threadIdx.x;
    const int lane  = tid & 63;
    const int wv    = tid >> 6;            // wave 0..1
    const int e_low = lane & 15;
    const int quad  = lane >> 4;           // k-octet / D-row group
    const int tok0  = blockIdx.x * BM;

    // per-lane expert bias for the 4 expert groups
    float bias4[4];
#pragma unroll
    for (int eg = 0; eg < 4; ++eg) bias4[eg] = b[eg * 16 + e_low];

    // x source: lane owns token (wv*16 + e_low), k-octet quad => A-frag direct
    const float* xrow = x + (size_t)(tok0 + wv * 16 + e_low) * DIM + quad * 8;

    // B-frag lane offset inside a 4KB array page: expert row e = eg*16+e_low,
    // swizzled chunk = quad ^ (e&3) = quad ^ (e_low&3)
    const int lane_woff = e_low * 64 + ((quad ^ (e_low & 3)) * 16);

    const int w6 = wv * 6;                 // 12 DMA segments split over 2 waves
    auto stageW = [&](int buf, int kc) {
#pragma unroll
        for (int i = 0; i < 6; ++i) {
            int seg = w6 + i;
            int a = seg >> 2, qt = seg & 3;
            gload16(ws + (size_t)a * WARR + (size_t)kc * 4096 + qt * 1024 + lane * 16,
                    &warena[buf][a][qt * 1024 + lane * 16]);
        }
    };

    f32x4 accm[4], accs[4];                // main (hh) and small-term accums
#pragma unroll
    for (int eg = 0; eg < 4; ++eg) {
        accm[eg] = (f32x4){0.f, 0.f, 0.f, 0.f};
        accs[eg] = (f32x4){0.f, 0.f, 0.f, 0.f};
    }

    // prologue
    stageW(0, 0);
    f32x4 cxa = *(const f32x4*)(xrow);
    f32x4 cxb = *(const f32x4*)(xrow + 4);
    __syncthreads();

    f32x4 nxa, nxb;
    for (int kc = 0; kc < NCH; ++kc) {
        const int buf = kc & 1;
        if (kc + 1 < NCH) {
            stageW(buf ^ 1, kc + 1);                       // DMA next W chunk
            nxa = *(const f32x4*)(xrow + (kc + 1) * 32);   // prefetch next x
            nxb = *(const f32x4*)(xrow + (kc + 1) * 32 + 4);
        }
        // convert 8 x-floats -> 3-way bf16 split A-fragments
        float xs[8] = {cxa.x, cxa.y, cxa.z, cxa.w, cxb.x, cxb.y, cxb.z, cxb.w};
        short8v xh, xl, xm;
#pragma unroll
        for (int i = 0; i < 8; ++i) {
            float bh, bl, bm;
            xh[i] = (short)rne_bf16(xs[i], bh);
            float r1 = xs[i] - bh;
            xl[i] = (short)rne_bf16(r1, bl);
            float r2 = r1 - bl;
            xm[i] = (short)rne_bf16(r2, bm);
        }
#pragma unroll
        for (int eg = 0; eg < 4; ++eg) {
            const char* pg = &warena[buf][0][0] + eg * 1024 + lane_woff;
            short8v bh = *(const short8v*)(pg);
            short8v bl = *(const short8v*)(pg + 4096);
            short8v bm = *(const short8v*)(pg + 8192);
            accm[eg] = __builtin_amdgcn_mfma_f32_16x16x32_bf16(xh, bh, accm[eg], 0, 0, 0);
            accs[eg] = __builtin_amdgcn_mfma_f32_16x16x32_bf16(xh, bl, accs[eg], 0, 0, 0);
            accs[eg] = __builtin_amdgcn_mfma_f32_16x16x32_bf16(xl, bh, accs[eg], 0, 0, 0);
            accs[eg] = __builtin_amdgcn_mfma_f32_16x16x32_bf16(xl, bl, accs[eg], 0, 0, 0);
            accs[eg] = __builtin_amdgcn_mfma_f32_16x16x32_bf16(xh, bm, accs[eg], 0, 0, 0);
            accs[eg] = __builtin_amdgcn_mfma_f32_16x16x32_bf16(xm, bh, accs[eg], 0, 0, 0);
        }
        __syncthreads();     // DMA kc+1 done; all reads of buf done
        cxa = nxa; cxb = nxb;
    }

    // ---- logits to LDS: D[row=(quad*4+q)][col=e_low] per eg ----
#pragma unroll
    for (int eg = 0; eg < 4; ++eg)
#pragma unroll
        for (int q = 0; q < 4; ++q) {
            int t = wv * 16 + quad * 4 + q;
            logits_s[t][eg * 16 + e_low] = accm[eg][q] + accs[eg][q] + bias4[eg];
        }
    __syncthreads();

    // ---- top-8 + softmax: one lane per token ----
    if (tid < BM) {
        const int t = tid;
        float pv[TOPK]; int pi[TOPK];
#pragma unroll
        for (int k = 0; k < TOPK; ++k) {
            float vmax = -INFINITY; int imax = 0;
#pragma unroll
            for (int e = 0; e < NEXP; ++e) {
                float v = logits_s[t][e];
                if (v > vmax) { vmax = v; imax = e; }   // strict > == lowest-index tie-break
            }
            pv[k] = vmax; pi[k] = imax;
            logits_s[t][imax] = -INFINITY;
        }
        float p[TOPK]; float s = 0.f;
#pragma unroll
        for (int k = 0; k < TOPK; ++k) { p[k] = __expf(pv[k] - pv[0]); s += p[k]; }
        float inv = 1.f / s;
#pragma unroll
        for (int e = 0; e < NEXP; ++e) logits_s[t][e] = 0.f;
#pragma unroll
        for (int k = 0; k < TOPK; ++k) {
            logits_s[t][pi[k]] = p[k] * inv;
            topk_s[t][k] = (float)pi[k];
        }
    }
    __syncthreads();

    // ---- coalesced outputs: probs 32x64 = 512 f4, 4/thread ----
#pragma unroll
    for (int it = 0; it < 4; ++it) {
        int v = tid + it * THREADS;
        int r = v >> 4, c4 = (v & 15) * 4;
        f32x4 z = {logits_s[r][c4], logits_s[r][c4 + 1],
                   logits_s[r][c4 + 2], logits_s[r][c4 + 3]};
        *(f32x4*)(out_probs + (size_t)(tok0 + r) * NEXP + c4) = z;
    }
    if (tid < 64) {                       // idx: 32x8 = 64 f4
        int r = tid >> 1, c4 = tid & 1;
        f32x4 z = *(const f32x4*)&topk_s[r][c4 * 4];
        *(f32x4*)(out_idx + (size_t)(tok0 + r) * TOPK + c4 * 4) = z;
    }
}

extern "C" void kernel_launch(void* const* d_in, const int* in_sizes, int n_in,
                              void* d_out, int out_size, void* d_ws, size_t ws_size,
                              hipStream_t stream) {
    const float* x = (const float*)d_in[0];
    const float* W = (const float*)d_in[1];
    const float* b = (const float*)d_in[2];
    float* out = (float*)d_out;

    const int ntok = in_sizes[0] / DIM;            // 32768
    float* out_probs = out;                         // [ntok, 64]
    float* out_idx   = out + (size_t)ntok * NEXP;   // [ntok, 8] as float values
    char*  ws        = (char*)d_ws;                 // 384 KB: Wh/Wl/Wm swizzled

    wconv_kernel<<<32, 256, 0, stream>>>(W, ws);
    router_fused_kernel<<<ntok / BM, THREADS, 0, stream>>>(x, ws, b, out_probs, out_idx);
}